// Round 4
// baseline (316.474 us; speedup 1.0000x reference)
//
#include <hip/hip_runtime.h>
#include <stdint.h>
#include <stddef.h>

#define SEQ 2048
#define NH 16
#define DH 64
#define DM 1024
#define NROWS 8192  // B*T

typedef __attribute__((ext_vector_type(4))) float f32x4;
typedef __attribute__((ext_vector_type(16))) float f32x16;
typedef __attribute__((ext_vector_type(8))) short s16x8;
typedef __attribute__((ext_vector_type(4))) unsigned u32x4;

__device__ __forceinline__ unsigned short f2bf(float f) {
  unsigned int u = __builtin_bit_cast(unsigned int, f);
  u += 0x7fffu + ((u >> 16) & 1u);
  return (unsigned short)(u >> 16);
}

__device__ __forceinline__ float exp2fast(float x) {
#if __has_builtin(__builtin_amdgcn_exp2f)
  return __builtin_amdgcn_exp2f(x);
#else
  return exp2f(x);
#endif
}

__device__ __forceinline__ float rcpfast(float x) {
#if __has_builtin(__builtin_amdgcn_rcpf)
  return __builtin_amdgcn_rcpf(x);
#else
  return 1.0f / x;
#endif
}

// pack two f32 -> (bf16(lo) | bf16(hi)<<16), truncating (P in (0,1], rel err < 2^-8)
__device__ __forceinline__ unsigned pk2(float lo, float hi) {
  return __builtin_amdgcn_perm(__builtin_bit_cast(unsigned, hi),
                               __builtin_bit_cast(unsigned, lo), 0x07060302u);
}

__device__ __forceinline__ void async16(const void* g, void* l) {
  __builtin_amdgcn_global_load_lds(
      (const __attribute__((address_space(1))) unsigned int*)g,
      (__attribute__((address_space(3))) unsigned int*)l, 16, 0, 0);
}

// ---------------- fused fp32 -> bf16 cast: x + 4 weights, one launch ----------------
// dsts: Xb (8M elems) then 4 weight matrices contiguous at Wb (4 x 1M elems)
__global__ __launch_bounds__(256) void cast_all(const float* __restrict__ x,
                                                const float* __restrict__ w0,
                                                const float* __restrict__ w1,
                                                const float* __restrict__ w2,
                                                const float* __restrict__ w3,
                                                short* __restrict__ Xb,
                                                short* __restrict__ Wb) {
  int g = blockIdx.x * 256 + threadIdx.x;  // chunk of 8 floats
  const float* src;
  short* dst;
  int off;
  if (g < NROWS * DM / 8) {
    src = x; dst = Xb; off = g;
  } else {
    int r = g - NROWS * DM / 8;
    int w = r >> 17;             // 0..3  (DM*DM/8 = 131072 chunks per weight)
    off = r & 131071;
    src = (w == 0) ? w0 : (w == 1) ? w1 : (w == 2) ? w2 : w3;
    dst = Wb + ((size_t)w << 20);
  }
  const float4* s4 = (const float4*)src;
  float4 a = s4[2 * off], b = s4[2 * off + 1];
  s16x8 o;
  o[0] = (short)f2bf(a.x); o[1] = (short)f2bf(a.y);
  o[2] = (short)f2bf(a.z); o[3] = (short)f2bf(a.w);
  o[4] = (short)f2bf(b.x); o[5] = (short)f2bf(b.y);
  o[6] = (short)f2bf(b.z); o[7] = (short)f2bf(b.w);
  *(s16x8*)(dst + (size_t)8 * off) = o;
}

// ---------------- fused QKV projection GEMM, BK=64 ----------------
// X [8192,1024] bf16; W [1024,1024] bf16 (rows = out features). blockIdx.x: 24 tiles
// of N; x>>3 selects Q/K/V. Q,K -> [B,NH,SEQ,DH]; V -> [B,NH,DH,SEQ] (operand-swapped
// MFMA so tokens land in lanes => coalesced stores along SEQ).
__global__ __launch_bounds__(256) void gemm_qkv(const short* __restrict__ X,
                                                const short* __restrict__ Wq,
                                                const short* __restrict__ Wk,
                                                const short* __restrict__ Wv,
                                                short* __restrict__ Qo,
                                                short* __restrict__ Ko,
                                                short* __restrict__ Vo) {
  __shared__ __align__(16) short As[128 * 64];
  __shared__ __align__(16) short Bs[128 * 64];
  const int tid = threadIdx.x;
  const int lane = tid & 63, wave = tid >> 6;
  const int l15 = lane & 15, quad = lane >> 4, lk8 = quad * 8;
  const int which = blockIdx.x >> 3;
  const int bn = (blockIdx.x & 7) * 128;
  const int bm = blockIdx.y * 128;
  const int wm = (wave >> 1) * 64, wn = (wave & 1) * 64;

  const short* Wsel = (which == 0) ? Wq : (which == 1) ? Wk : Wv;
  const short* Ab = X + (size_t)bm * DM;
  const short* Bb = Wsel + (size_t)bn * DM;

  f32x4 acc[4][4];
#pragma unroll
  for (int i = 0; i < 4; i++)
#pragma unroll
    for (int j = 0; j < 4; j++) acc[i][j] = (f32x4)0.f;

  const int srow = tid >> 3, scol = (tid & 7) * 8;

  for (int k0 = 0; k0 < DM; k0 += 64) {
#pragma unroll
    for (int i = 0; i < 4; i++) {
      int row = i * 32 + srow;
      async16(Ab + (size_t)row * DM + k0 + scol, As + ((size_t)(i * 256 + tid)) * 8);
      async16(Bb + (size_t)row * DM + k0 + scol, Bs + ((size_t)(i * 256 + tid)) * 8);
    }
    __syncthreads();
    if (which == 2) {
#pragma unroll
      for (int ks = 0; ks < 2; ks++) {
        s16x8 af[4], bfr[4];
#pragma unroll
        for (int t = 0; t < 4; t++) af[t] = *(const s16x8*)(As + (wm + t * 16 + l15) * 64 + ks * 32 + lk8);
#pragma unroll
        for (int t = 0; t < 4; t++) bfr[t] = *(const s16x8*)(Bs + (wn + t * 16 + l15) * 64 + ks * 32 + lk8);
#pragma unroll
        for (int mt = 0; mt < 4; mt++)
#pragma unroll
          for (int nt = 0; nt < 4; nt++)
            acc[mt][nt] = __builtin_amdgcn_mfma_f32_16x16x32_bf16(bfr[nt], af[mt], acc[mt][nt], 0, 0, 0);
      }
    } else {
#pragma unroll
      for (int ks = 0; ks < 2; ks++) {
        s16x8 af[4], bfr[4];
#pragma unroll
        for (int t = 0; t < 4; t++) af[t] = *(const s16x8*)(As + (wm + t * 16 + l15) * 64 + ks * 32 + lk8);
#pragma unroll
        for (int t = 0; t < 4; t++) bfr[t] = *(const s16x8*)(Bs + (wn + t * 16 + l15) * 64 + ks * 32 + lk8);
#pragma unroll
        for (int mt = 0; mt < 4; mt++)
#pragma unroll
          for (int nt = 0; nt < 4; nt++)
            acc[mt][nt] = __builtin_amdgcn_mfma_f32_16x16x32_bf16(af[mt], bfr[nt], acc[mt][nt], 0, 0, 0);
      }
    }
    __syncthreads();
  }

  if (which == 2) {
#pragma unroll
    for (int mt = 0; mt < 4; mt++)
#pragma unroll
      for (int r = 0; r < 4; r++)
#pragma unroll
        for (int nt = 0; nt < 4; nt++) {
          int n = bn + wn + nt * 16 + quad * 4 + r;  // d-dim
          int m = bm + wm + mt * 16 + l15;           // token
          int b = m >> 11, t = m & (SEQ - 1);
          int hh = n >> 6, d = n & 63;
          Vo[(((size_t)b * NH + hh) * DH + d) * SEQ + t] = (short)f2bf(acc[mt][nt][r]);
        }
  } else {
    short* Dst = (which == 0) ? Qo : Ko;
#pragma unroll
    for (int mt = 0; mt < 4; mt++)
#pragma unroll
      for (int r = 0; r < 4; r++)
#pragma unroll
        for (int nt = 0; nt < 4; nt++) {
          int m = bm + wm + mt * 16 + quad * 4 + r;
          int n = bn + wn + nt * 16 + l15;
          int b = m >> 11, t = m & (SEQ - 1);
          int hh = n >> 6, d = n & 63;
          Dst[((((size_t)b * NH + hh) * SEQ + t) << 6) + d] = (short)f2bf(acc[mt][nt][r]);
        }
  }
}

// ---------------- output projection GEMM, BK=64, fp32 out ----------------
__global__ __launch_bounds__(256) void gemm_o(const short* __restrict__ A,
                                              const short* __restrict__ B,
                                              float* __restrict__ C) {
  __shared__ __align__(16) short As[128 * 64];
  __shared__ __align__(16) short Bs[128 * 64];
  const int tid = threadIdx.x;
  const int lane = tid & 63, wave = tid >> 6;
  const int l15 = lane & 15, quad = lane >> 4, lk8 = quad * 8;
  const int bm = blockIdx.y * 128, bn = blockIdx.x * 128;
  const int wm = (wave >> 1) * 64, wn = (wave & 1) * 64;

  const short* Ab = A + (size_t)bm * DM;
  const short* Bb = B + (size_t)bn * DM;

  f32x4 acc[4][4];
#pragma unroll
  for (int i = 0; i < 4; i++)
#pragma unroll
    for (int j = 0; j < 4; j++) acc[i][j] = (f32x4)0.f;

  const int srow = tid >> 3, scol = (tid & 7) * 8;

  for (int k0 = 0; k0 < DM; k0 += 64) {
#pragma unroll
    for (int i = 0; i < 4; i++) {
      int row = i * 32 + srow;
      async16(Ab + (size_t)row * DM + k0 + scol, As + ((size_t)(i * 256 + tid)) * 8);
      async16(Bb + (size_t)row * DM + k0 + scol, Bs + ((size_t)(i * 256 + tid)) * 8);
    }
    __syncthreads();
#pragma unroll
    for (int ks = 0; ks < 2; ks++) {
      s16x8 af[4], bfr[4];
#pragma unroll
      for (int t = 0; t < 4; t++) af[t] = *(const s16x8*)(As + (wm + t * 16 + l15) * 64 + ks * 32 + lk8);
#pragma unroll
      for (int t = 0; t < 4; t++) bfr[t] = *(const s16x8*)(Bs + (wn + t * 16 + l15) * 64 + ks * 32 + lk8);
#pragma unroll
      for (int mt = 0; mt < 4; mt++)
#pragma unroll
        for (int nt = 0; nt < 4; nt++)
          acc[mt][nt] = __builtin_amdgcn_mfma_f32_16x16x32_bf16(af[mt], bfr[nt], acc[mt][nt], 0, 0, 0);
    }
    __syncthreads();
  }

#pragma unroll
  for (int mt = 0; mt < 4; mt++)
#pragma unroll
    for (int r = 0; r < 4; r++) {
      int m = bm + wm + mt * 16 + quad * 4 + r;
#pragma unroll
      for (int nt = 0; nt < 4; nt++)
        C[(size_t)m * DM + bn + wn + nt * 16 + l15] = acc[mt][nt][r];
    }
}

// ---------------- causal flash attention, paired q-tiles ----------------
// Each block handles q-tiles (a, 15-a) of one head, sharing staged K/V: exactly 17
// q-tile-computes per block (uniform work). Grid 512 = 2 blocks/CU all-resident.
// blockIdx&7 -> XCD, 8 heads per XCD so each head's 512KB K/V stays in its XCD L2.
__global__ __launch_bounds__(256, 2) void attn_kernel(const short* __restrict__ Q,
                                                      const short* __restrict__ K,
                                                      const short* __restrict__ V,
                                                      short* __restrict__ O) {
  __shared__ __align__(16) short Smem[2 * 16384];  // 2 x (K 16KB + V 16KB) = 64KB

  const int tid = threadIdx.x;
  const int lane = tid & 63, wave = tid >> 6;
  const int l31 = lane & 31, h = lane >> 5;

  const int cxcd = blockIdx.x & 7, s = blockIdx.x >> 3;
  const int bh = cxcd * 8 + (s >> 3);
  const int a = s & 7;
  const int qta = a, qtb = 15 - a;

  const short* Qb = Q + (size_t)bh * SEQ * DH;
  const short* Kb = K + (size_t)bh * SEQ * DH;
  const short* Vb = V + (size_t)bh * DH * SEQ;

  auto stage = [&](int ktile, int bufsel) {
    short* base = Smem + bufsel * 16384;
    const short* ksrc = Kb + (size_t)ktile * 128 * DH;
#pragma unroll
    for (int i = 0; i < 4; i++) {
      int f = i * 256 + tid;
      int kk = f >> 3, c8 = (f & 7) ^ (kk & 7);
      async16(ksrc + (size_t)kk * DH + c8 * 8, base + (size_t)f * 8);
    }
    const short* vsrc = Vb + (size_t)ktile * 128;
#pragma unroll
    for (int i = 0; i < 4; i++) {
      int f = i * 256 + tid;
      int d = f >> 4, c16 = (f & 15) ^ (d & 15);
      async16(vsrc + (size_t)d * SEQ + c16 * 8, base + 8192 + (size_t)f * 8);
    }
  };

  const float C = 0.18033688011112042f;  // (1/sqrt(64)) * log2(e)

  // one flash step for one q-tile against the staged K/V tile
  auto step = [&](bool diag, const s16x8 (&qf)[4], f32x16 (&oacc)[2],
                  float& m_own, float& l_own, const short* Ks, const short* Vs) {
    f32x16 sacc[4];
#pragma unroll
    for (int T = 0; T < 4; T++) sacc[T] = (f32x16)0.f;
#pragma unroll
    for (int ks = 0; ks < 4; ks++) {
#pragma unroll
      for (int T = 0; T < 4; T++) {
        s16x8 kf = *(const s16x8*)(Ks + (T * 32 + l31) * 64 + (((2 * ks + h) ^ (l31 & 7)) * 8));
        sacc[T] = __builtin_amdgcn_mfma_f32_32x32x16_bf16(kf, qf[ks], sacc[T], 0, 0, 0);
      }
    }
    if (diag) {
      int limit = wave * 32 + l31 - 4 * h;
#pragma unroll
      for (int T = 0; T < 4; T++)
#pragma unroll
        for (int r = 0; r < 16; r++) {
          int kkc = T * 32 + (r & 3) + 8 * (r >> 2);
          if (kkc > limit) sacc[T][r] = -3.0e38f;
        }
    }
    float tm[4];
#pragma unroll
    for (int T = 0; T < 4; T++) {
      float x0 = fmaxf(fmaxf(sacc[T][0], sacc[T][1]), fmaxf(sacc[T][2], sacc[T][3]));
      float x1 = fmaxf(fmaxf(sacc[T][4], sacc[T][5]), fmaxf(sacc[T][6], sacc[T][7]));
      float x2 = fmaxf(fmaxf(sacc[T][8], sacc[T][9]), fmaxf(sacc[T][10], sacc[T][11]));
      float x3 = fmaxf(fmaxf(sacc[T][12], sacc[T][13]), fmaxf(sacc[T][14], sacc[T][15]));
      tm[T] = fmaxf(fmaxf(x0, x1), fmaxf(x2, x3));
    }
    float mx = fmaxf(fmaxf(tm[0], tm[1]), fmaxf(tm[2], tm[3]));
    mx = fmaxf(mx, __shfl_xor(mx, 32, 64));
    float mnew = fmaxf(m_own, mx);
    float mb = mnew * C;
    float alpha = exp2fast(m_own * C - mb);
    m_own = mnew;

    float ts[4];
#pragma unroll
    for (int T = 0; T < 4; T++) {
#pragma unroll
      for (int r = 0; r < 16; r++) sacc[T][r] = exp2fast(fmaf(sacc[T][r], C, -mb));
      float x0 = (sacc[T][0] + sacc[T][1]) + (sacc[T][2] + sacc[T][3]);
      float x1 = (sacc[T][4] + sacc[T][5]) + (sacc[T][6] + sacc[T][7]);
      float x2 = (sacc[T][8] + sacc[T][9]) + (sacc[T][10] + sacc[T][11]);
      float x3 = (sacc[T][12] + sacc[T][13]) + (sacc[T][14] + sacc[T][15]);
      ts[T] = (x0 + x1) + (x2 + x3);
    }
    float rsum = (ts[0] + ts[1]) + (ts[2] + ts[3]);
    rsum += __shfl_xor(rsum, 32, 64);
    l_own = l_own * alpha + rsum;

    s16x8 pf[8];
#pragma unroll
    for (int T = 0; T < 4; T++) {
      unsigned P0 = pk2(sacc[T][0], sacc[T][1]);
      unsigned P1 = pk2(sacc[T][2], sacc[T][3]);
      unsigned P2 = pk2(sacc[T][4], sacc[T][5]);
      unsigned P3 = pk2(sacc[T][6], sacc[T][7]);
      unsigned P4 = pk2(sacc[T][8], sacc[T][9]);
      unsigned P5 = pk2(sacc[T][10], sacc[T][11]);
      unsigned P6 = pk2(sacc[T][12], sacc[T][13]);
      unsigned P7 = pk2(sacc[T][14], sacc[T][15]);
      unsigned R0 = (unsigned)__shfl_xor((int)(h ? P0 : P2), 32, 64);
      unsigned R1 = (unsigned)__shfl_xor((int)(h ? P1 : P3), 32, 64);
      unsigned R2 = (unsigned)__shfl_xor((int)(h ? P4 : P6), 32, 64);
      unsigned R3 = (unsigned)__shfl_xor((int)(h ? P5 : P7), 32, 64);
      u32x4 lo, hi;
      lo[0] = h ? R0 : P0; lo[1] = h ? R1 : P1; lo[2] = h ? P2 : R0; lo[3] = h ? P3 : R1;
      hi[0] = h ? R2 : P4; hi[1] = h ? R3 : P5; hi[2] = h ? P6 : R2; hi[3] = h ? P7 : R3;
      pf[2 * T] = __builtin_bit_cast(s16x8, lo);
      pf[2 * T + 1] = __builtin_bit_cast(s16x8, hi);
    }

#pragma unroll
    for (int r = 0; r < 16; r++) {
      oacc[0][r] *= alpha;
      oacc[1][r] *= alpha;
    }
#pragma unroll
    for (int kc = 0; kc < 8; kc++) {
#pragma unroll
      for (int td = 0; td < 2; td++) {
        s16x8 vf = *(const s16x8*)(Vs + (td * 32 + l31) * 128 + (((2 * kc + h) ^ (l31 & 15)) * 8));
        oacc[td] = __builtin_amdgcn_mfma_f32_32x32x16_bf16(vf, pf[kc], oacc[td], 0, 0, 0);
      }
    }
  };

  // Q fragments for both tiles: B[k=ks*16+h*8+j][n=q=l31]
  s16x8 qfa[4], qfb[4];
#pragma unroll
  for (int ks = 0; ks < 4; ks++) {
    qfa[ks] = *(const s16x8*)(Qb + (size_t)(qta * 128 + wave * 32 + l31) * DH + ks * 16 + h * 8);
    qfb[ks] = *(const s16x8*)(Qb + (size_t)(qtb * 128 + wave * 32 + l31) * DH + ks * 16 + h * 8);
  }

  f32x16 oA[2], oB[2];
  oA[0] = (f32x16)0.f; oA[1] = (f32x16)0.f;
  oB[0] = (f32x16)0.f; oB[1] = (f32x16)0.f;
  float mA = -3.0e38f, lA = 0.f, mB = -3.0e38f, lB = 0.f;

  stage(0, 0);

  for (int kt = 0; kt <= qtb; kt++) {
    const int cur = kt & 1;
    __syncthreads();  // buf[cur] ready (its loads aged one full compute phase)
    if (kt < qtb) stage(kt + 1, cur ^ 1);
    const short* Ks = Smem + cur * 16384;
    const short* Vs = Ks + 8192;
    if (kt <= qta) step(kt == qta, qfa, oA, mA, lA, Ks, Vs);
    step(kt == qtb, qfb, oB, mB, lB, Ks, Vs);
  }

  // ---- epilogue: transpose O^T -> O via padded LDS, coalesced store ----
  __syncthreads();  // all waves done with K/V buffers
  const int b = bh >> 4, head = bh & 15;
  const int g = lane >> 3, d4 = (lane & 7) * 4;

  auto epilogue = [&](int q0, f32x16 (&oacc)[2], float l_own) {
    float inv = rcpfast(l_own);
#pragma unroll
    for (int td = 0; td < 2; td++) {
      float* tb = (float*)Smem + (size_t)(wave * 2 + td) * 1056;  // 32 d-rows x 33 (pad)
#pragma unroll
      for (int r = 0; r < 16; r++) {
        int d_loc = (r & 3) + 8 * (r >> 2) + 4 * h;
        tb[d_loc * 33 + l31] = oacc[td][r] * inv;
      }
      // same-wave DS ops are in-order: reads see this wave's writes
#pragma unroll
      for (int j = 0; j < 4; j++) {
        int qq = j * 8 + g;
        float x0 = tb[(d4 + 0) * 33 + qq];
        float x1 = tb[(d4 + 1) * 33 + qq];
        float x2 = tb[(d4 + 2) * 33 + qq];
        float x3 = tb[(d4 + 3) * 33 + qq];
        uint2 pkd;
        pkd.x = (unsigned)f2bf(x0) | ((unsigned)f2bf(x1) << 16);
        pkd.y = (unsigned)f2bf(x2) | ((unsigned)f2bf(x3) << 16);
        int q = q0 + wave * 32 + qq;
        *(uint2*)(O + ((size_t)(b * SEQ + q)) * DM + head * DH + td * 32 + d4) = pkd;
      }
    }
  };
  epilogue(qta * 128, oA, lA);
  epilogue(qtb * 128, oB, lB);
}

// ---------------- host launch ----------------
extern "C" void kernel_launch(void* const* d_in, const int* in_sizes, int n_in,
                              void* d_out, int out_size, void* d_ws, size_t ws_size,
                              hipStream_t stream) {
  const float* x  = (const float*)d_in[0];
  const float* wq = (const float*)d_in[1];
  const float* wk = (const float*)d_in[2];
  const float* wv = (const float*)d_in[3];
  const float* wo = (const float*)d_in[4];

  short* ws = (short*)d_ws;
  short* Xb  = ws;
  short* Wqb = Xb + (size_t)NROWS * DM;     // 4 weights contiguous from here
  short* Wkb = Wqb + (size_t)DM * DM;
  short* Wvb = Wkb + (size_t)DM * DM;
  short* Wob = Wvb + (size_t)DM * DM;
  short* Qb  = Wob + (size_t)DM * DM;       // [B,NH,SEQ,DH]
  short* Kb  = Qb + (size_t)NROWS * DM;
  short* Vtb = Kb + (size_t)NROWS * DM;     // [B,NH,DH,SEQ]
  short* Ob  = Xb;                          // alias: X dead after QKV GEMMs

  int total_chunks = NROWS * DM / 8 + 4 * (DM * DM / 8);
  cast_all<<<total_chunks / 256, 256, 0, stream>>>(x, wq, wk, wv, wo, Xb, Wqb);

  gemm_qkv<<<dim3(24, 64), 256, 0, stream>>>(Xb, Wqb, Wkb, Wvb, Qb, Kb, Vtb);

  attn_kernel<<<512, 256, 0, stream>>>(Qb, Kb, Vtb, Ob);

  gemm_o<<<dim3(8, 64), 256, 0, stream>>>(Ob, Wob, (float*)d_out);
}

// Round 5
// 309.525 us; speedup vs baseline: 1.0225x; 1.0225x over previous
//
#include <hip/hip_runtime.h>
#include <stdint.h>
#include <stddef.h>

#define SEQ 2048
#define NH 16
#define DH 64
#define DM 1024
#define NROWS 8192  // B*T

typedef __attribute__((ext_vector_type(4))) float f32x4;
typedef __attribute__((ext_vector_type(16))) float f32x16;
typedef __attribute__((ext_vector_type(8))) short s16x8;
typedef __attribute__((ext_vector_type(4))) unsigned u32x4;

__device__ __forceinline__ unsigned short f2bf(float f) {
  unsigned int u = __builtin_bit_cast(unsigned int, f);
  u += 0x7fffu + ((u >> 16) & 1u);
  return (unsigned short)(u >> 16);
}

__device__ __forceinline__ float exp2fast(float x) {
#if __has_builtin(__builtin_amdgcn_exp2f)
  return __builtin_amdgcn_exp2f(x);
#else
  return exp2f(x);
#endif
}

__device__ __forceinline__ float rcpfast(float x) {
#if __has_builtin(__builtin_amdgcn_rcpf)
  return __builtin_amdgcn_rcpf(x);
#else
  return 1.0f / x;
#endif
}

// pack two f32 -> (bf16(lo) | bf16(hi)<<16), truncating (P in (0,1], rel err < 2^-8)
__device__ __forceinline__ unsigned pk2(float lo, float hi) {
  return __builtin_amdgcn_perm(__builtin_bit_cast(unsigned, hi),
                               __builtin_bit_cast(unsigned, lo), 0x07060302u);
}

__device__ __forceinline__ void async16(const void* g, void* l) {
  __builtin_amdgcn_global_load_lds(
      (const __attribute__((address_space(1))) unsigned int*)g,
      (__attribute__((address_space(3))) unsigned int*)l, 16, 0, 0);
}

// ---------------- fused fp32 -> bf16 cast: x + 4 weights, one launch ----------------
__global__ __launch_bounds__(256) void cast_all(const float* __restrict__ x,
                                                const float* __restrict__ w0,
                                                const float* __restrict__ w1,
                                                const float* __restrict__ w2,
                                                const float* __restrict__ w3,
                                                short* __restrict__ Xb,
                                                short* __restrict__ Wb) {
  int g = blockIdx.x * 256 + threadIdx.x;  // chunk of 8 floats
  const float* src;
  short* dst;
  int off;
  if (g < NROWS * DM / 8) {
    src = x; dst = Xb; off = g;
  } else {
    int r = g - NROWS * DM / 8;
    int w = r >> 17;             // 0..3  (DM*DM/8 = 131072 chunks per weight)
    off = r & 131071;
    src = (w == 0) ? w0 : (w == 1) ? w1 : (w == 2) ? w2 : w3;
    dst = Wb + ((size_t)w << 20);
  }
  const float4* s4 = (const float4*)src;
  float4 a = s4[2 * off], b = s4[2 * off + 1];
  s16x8 o;
  o[0] = (short)f2bf(a.x); o[1] = (short)f2bf(a.y);
  o[2] = (short)f2bf(a.z); o[3] = (short)f2bf(a.w);
  o[4] = (short)f2bf(b.x); o[5] = (short)f2bf(b.y);
  o[6] = (short)f2bf(b.z); o[7] = (short)f2bf(b.w);
  *(s16x8*)(dst + (size_t)8 * off) = o;
}

// ---------------- fused QKV projection GEMM, BK=64, XOR-swizzled LDS ----------------
// LDS tile 128 rows x 64 shorts (128B row = 32 banks): without swizzle the 16 l15-rows
// of a fragment read alias to one 4-bank group (16-way conflict, m136: 5.7x). Store
// physical chunk p of row r as logical chunk p^(r&7); reads compensate -> all 32 banks
// covered at 2 lanes/bank (free).
__global__ __launch_bounds__(256) void gemm_qkv(const short* __restrict__ X,
                                                const short* __restrict__ Wq,
                                                const short* __restrict__ Wk,
                                                const short* __restrict__ Wv,
                                                short* __restrict__ Qo,
                                                short* __restrict__ Ko,
                                                short* __restrict__ Vo) {
  __shared__ __align__(16) short As[128 * 64];
  __shared__ __align__(16) short Bs[128 * 64];
  const int tid = threadIdx.x;
  const int lane = tid & 63, wave = tid >> 6;
  const int l15 = lane & 15, quad = lane >> 4;
  const int which = blockIdx.x >> 3;
  const int bn = (blockIdx.x & 7) * 128;
  const int bm = blockIdx.y * 128;
  const int wm = (wave >> 1) * 64, wn = (wave & 1) * 64;

  const short* Wsel = (which == 0) ? Wq : (which == 1) ? Wk : Wv;
  const short* Ab = X + (size_t)bm * DM;
  const short* Bb = Wsel + (size_t)bn * DM;

  f32x4 acc[4][4];
#pragma unroll
  for (int i = 0; i < 4; i++)
#pragma unroll
    for (int j = 0; j < 4; j++) acc[i][j] = (f32x4)0.f;

  const int srow = tid >> 3;                              // row within 32-row group
  const int scol = ((tid & 7) ^ (srow & 7)) * 8;          // swizzled source chunk

  for (int k0 = 0; k0 < DM; k0 += 64) {
#pragma unroll
    for (int i = 0; i < 4; i++) {
      int row = i * 32 + srow;
      async16(Ab + (size_t)row * DM + k0 + scol, As + ((size_t)(i * 256 + tid)) * 8);
      async16(Bb + (size_t)row * DM + k0 + scol, Bs + ((size_t)(i * 256 + tid)) * 8);
    }
    __syncthreads();
    if (which == 2) {
#pragma unroll
      for (int ks = 0; ks < 2; ks++) {
        s16x8 af[4], bfr[4];
#pragma unroll
        for (int t = 0; t < 4; t++)
          af[t] = *(const s16x8*)(As + (wm + t * 16 + l15) * 64 + (((ks * 4 + quad) ^ (l15 & 7)) * 8));
#pragma unroll
        for (int t = 0; t < 4; t++)
          bfr[t] = *(const s16x8*)(Bs + (wn + t * 16 + l15) * 64 + (((ks * 4 + quad) ^ (l15 & 7)) * 8));
#pragma unroll
        for (int mt = 0; mt < 4; mt++)
#pragma unroll
          for (int nt = 0; nt < 4; nt++)
            acc[mt][nt] = __builtin_amdgcn_mfma_f32_16x16x32_bf16(bfr[nt], af[mt], acc[mt][nt], 0, 0, 0);
      }
    } else {
#pragma unroll
      for (int ks = 0; ks < 2; ks++) {
        s16x8 af[4], bfr[4];
#pragma unroll
        for (int t = 0; t < 4; t++)
          af[t] = *(const s16x8*)(As + (wm + t * 16 + l15) * 64 + (((ks * 4 + quad) ^ (l15 & 7)) * 8));
#pragma unroll
        for (int t = 0; t < 4; t++)
          bfr[t] = *(const s16x8*)(Bs + (wn + t * 16 + l15) * 64 + (((ks * 4 + quad) ^ (l15 & 7)) * 8));
#pragma unroll
        for (int mt = 0; mt < 4; mt++)
#pragma unroll
          for (int nt = 0; nt < 4; nt++)
            acc[mt][nt] = __builtin_amdgcn_mfma_f32_16x16x32_bf16(af[mt], bfr[nt], acc[mt][nt], 0, 0, 0);
      }
    }
    __syncthreads();
  }

  if (which == 2) {
#pragma unroll
    for (int mt = 0; mt < 4; mt++)
#pragma unroll
      for (int r = 0; r < 4; r++)
#pragma unroll
        for (int nt = 0; nt < 4; nt++) {
          int n = bn + wn + nt * 16 + quad * 4 + r;  // d-dim
          int m = bm + wm + mt * 16 + l15;           // token
          int b = m >> 11, t = m & (SEQ - 1);
          int hh = n >> 6, d = n & 63;
          Vo[(((size_t)b * NH + hh) * DH + d) * SEQ + t] = (short)f2bf(acc[mt][nt][r]);
        }
  } else {
    short* Dst = (which == 0) ? Qo : Ko;
#pragma unroll
    for (int mt = 0; mt < 4; mt++)
#pragma unroll
      for (int r = 0; r < 4; r++)
#pragma unroll
        for (int nt = 0; nt < 4; nt++) {
          int m = bm + wm + mt * 16 + quad * 4 + r;
          int n = bn + wn + nt * 16 + l15;
          int b = m >> 11, t = m & (SEQ - 1);
          int hh = n >> 6, d = n & 63;
          Dst[((((size_t)b * NH + hh) * SEQ + t) << 6) + d] = (short)f2bf(acc[mt][nt][r]);
        }
  }
}

// ---------------- output projection GEMM, BK=64, swizzled, fp32 out ----------------
__global__ __launch_bounds__(256) void gemm_o(const short* __restrict__ A,
                                              const short* __restrict__ B,
                                              float* __restrict__ C) {
  __shared__ __align__(16) short As[128 * 64];
  __shared__ __align__(16) short Bs[128 * 64];
  const int tid = threadIdx.x;
  const int lane = tid & 63, wave = tid >> 6;
  const int l15 = lane & 15, quad = lane >> 4;
  const int bm = blockIdx.y * 128, bn = blockIdx.x * 128;
  const int wm = (wave >> 1) * 64, wn = (wave & 1) * 64;

  const short* Ab = A + (size_t)bm * DM;
  const short* Bb = B + (size_t)bn * DM;

  f32x4 acc[4][4];
#pragma unroll
  for (int i = 0; i < 4; i++)
#pragma unroll
    for (int j = 0; j < 4; j++) acc[i][j] = (f32x4)0.f;

  const int srow = tid >> 3;
  const int scol = ((tid & 7) ^ (srow & 7)) * 8;

  for (int k0 = 0; k0 < DM; k0 += 64) {
#pragma unroll
    for (int i = 0; i < 4; i++) {
      int row = i * 32 + srow;
      async16(Ab + (size_t)row * DM + k0 + scol, As + ((size_t)(i * 256 + tid)) * 8);
      async16(Bb + (size_t)row * DM + k0 + scol, Bs + ((size_t)(i * 256 + tid)) * 8);
    }
    __syncthreads();
#pragma unroll
    for (int ks = 0; ks < 2; ks++) {
      s16x8 af[4], bfr[4];
#pragma unroll
      for (int t = 0; t < 4; t++)
        af[t] = *(const s16x8*)(As + (wm + t * 16 + l15) * 64 + (((ks * 4 + quad) ^ (l15 & 7)) * 8));
#pragma unroll
      for (int t = 0; t < 4; t++)
        bfr[t] = *(const s16x8*)(Bs + (wn + t * 16 + l15) * 64 + (((ks * 4 + quad) ^ (l15 & 7)) * 8));
#pragma unroll
      for (int mt = 0; mt < 4; mt++)
#pragma unroll
        for (int nt = 0; nt < 4; nt++)
          acc[mt][nt] = __builtin_amdgcn_mfma_f32_16x16x32_bf16(af[mt], bfr[nt], acc[mt][nt], 0, 0, 0);
    }
    __syncthreads();
  }

#pragma unroll
  for (int mt = 0; mt < 4; mt++)
#pragma unroll
    for (int r = 0; r < 4; r++) {
      int m = bm + wm + mt * 16 + quad * 4 + r;
#pragma unroll
      for (int nt = 0; nt < 4; nt++)
        C[(size_t)m * DM + bn + wn + nt * 16 + l15] = acc[mt][nt][r];
    }
}

// ---------------- causal flash attention (R3 version: 92.6us measured) ----------------
// S^T = K Q^T (q in lanes) -> lane-local softmax -> O^T = V^T P^T. Double-buffered LDS,
// one barrier per K-tile. blockIdx&7 -> XCD, 8 heads/XCD: head's 512KB K/V stays in L2.
__global__ __launch_bounds__(256, 2) void attn_kernel(const short* __restrict__ Q,
                                                      const short* __restrict__ K,
                                                      const short* __restrict__ V,
                                                      short* __restrict__ O) {
  __shared__ __align__(16) short Smem[2 * 16384];  // 2 x (K 16KB + V 16KB) = 64KB

  const int tid = threadIdx.x;
  const int lane = tid & 63, wave = tid >> 6;
  const int l31 = lane & 31, h = lane >> 5;

  const int c = blockIdx.x & 7, s = blockIdx.x >> 3;
  const int bh = c * 8 + (s >> 4);
  const int qt = 15 - (s & 15);
  const int q0 = qt * 128;

  const short* Qb = Q + (size_t)bh * SEQ * DH;
  const short* Kb = K + (size_t)bh * SEQ * DH;
  const short* Vb = V + (size_t)bh * DH * SEQ;

  auto stage = [&](int ktile, int bufsel) {
    short* base = Smem + bufsel * 16384;
    const short* ksrc = Kb + (size_t)ktile * 128 * DH;
#pragma unroll
    for (int i = 0; i < 4; i++) {
      int f = i * 256 + tid;
      int kk = f >> 3, c8 = (f & 7) ^ (kk & 7);
      async16(ksrc + (size_t)kk * DH + c8 * 8, base + (size_t)f * 8);
    }
    const short* vsrc = Vb + (size_t)ktile * 128;
#pragma unroll
    for (int i = 0; i < 4; i++) {
      int f = i * 256 + tid;
      int d = f >> 4, c16 = (f & 15) ^ (d & 15);
      async16(vsrc + (size_t)d * SEQ + c16 * 8, base + 8192 + (size_t)f * 8);
    }
  };

  s16x8 qf[4];
#pragma unroll
  for (int ks = 0; ks < 4; ks++)
    qf[ks] = *(const s16x8*)(Qb + (size_t)(q0 + wave * 32 + l31) * DH + ks * 16 + h * 8);

  f32x16 oacc[2];
  oacc[0] = (f32x16)0.f;
  oacc[1] = (f32x16)0.f;
  float m_own = -3.0e38f, l_own = 0.f;
  const float C = 0.18033688011112042f;  // (1/sqrt(64)) * log2(e)

  stage(0, 0);

  for (int kt = 0; kt <= qt; kt++) {
    const int cur = kt & 1;
    __syncthreads();  // buf[cur] ready (its loads aged one full compute phase)
    if (kt < qt) stage(kt + 1, cur ^ 1);
    const short* Ks = Smem + cur * 16384;
    const short* Vs = Ks + 8192;

    f32x16 sacc[4];
#pragma unroll
    for (int T = 0; T < 4; T++) sacc[T] = (f32x16)0.f;
#pragma unroll
    for (int ks = 0; ks < 4; ks++) {
#pragma unroll
      for (int T = 0; T < 4; T++) {
        s16x8 kf = *(const s16x8*)(Ks + (T * 32 + l31) * 64 + (((2 * ks + h) ^ (l31 & 7)) * 8));
        sacc[T] = __builtin_amdgcn_mfma_f32_32x32x16_bf16(kf, qf[ks], sacc[T], 0, 0, 0);
      }
    }

    if (kt == qt) {
      int limit = wave * 32 + l31 - 4 * h;
#pragma unroll
      for (int T = 0; T < 4; T++)
#pragma unroll
        for (int r = 0; r < 16; r++) {
          int kkc = T * 32 + (r & 3) + 8 * (r >> 2);
          if (kkc > limit) sacc[T][r] = -3.0e38f;
        }
    }

    float tm[4];
#pragma unroll
    for (int T = 0; T < 4; T++) {
      float a = fmaxf(fmaxf(sacc[T][0], sacc[T][1]), fmaxf(sacc[T][2], sacc[T][3]));
      float b = fmaxf(fmaxf(sacc[T][4], sacc[T][5]), fmaxf(sacc[T][6], sacc[T][7]));
      float cc = fmaxf(fmaxf(sacc[T][8], sacc[T][9]), fmaxf(sacc[T][10], sacc[T][11]));
      float d = fmaxf(fmaxf(sacc[T][12], sacc[T][13]), fmaxf(sacc[T][14], sacc[T][15]));
      tm[T] = fmaxf(fmaxf(a, b), fmaxf(cc, d));
    }
    float mx = fmaxf(fmaxf(tm[0], tm[1]), fmaxf(tm[2], tm[3]));
    mx = fmaxf(mx, __shfl_xor(mx, 32, 64));
    float mnew = fmaxf(m_own, mx);
    float mb = mnew * C;
    float alpha = exp2fast(m_own * C - mb);
    m_own = mnew;

    float ts[4];
#pragma unroll
    for (int T = 0; T < 4; T++) {
#pragma unroll
      for (int r = 0; r < 16; r++) sacc[T][r] = exp2fast(fmaf(sacc[T][r], C, -mb));
      float a = (sacc[T][0] + sacc[T][1]) + (sacc[T][2] + sacc[T][3]);
      float b = (sacc[T][4] + sacc[T][5]) + (sacc[T][6] + sacc[T][7]);
      float cc = (sacc[T][8] + sacc[T][9]) + (sacc[T][10] + sacc[T][11]);
      float d = (sacc[T][12] + sacc[T][13]) + (sacc[T][14] + sacc[T][15]);
      ts[T] = (a + b) + (cc + d);
    }
    float rsum = (ts[0] + ts[1]) + (ts[2] + ts[3]);
    rsum += __shfl_xor(rsum, 32, 64);
    l_own = l_own * alpha + rsum;

    s16x8 pf[8];
#pragma unroll
    for (int T = 0; T < 4; T++) {
      unsigned P0 = pk2(sacc[T][0], sacc[T][1]);
      unsigned P1 = pk2(sacc[T][2], sacc[T][3]);
      unsigned P2 = pk2(sacc[T][4], sacc[T][5]);
      unsigned P3 = pk2(sacc[T][6], sacc[T][7]);
      unsigned P4 = pk2(sacc[T][8], sacc[T][9]);
      unsigned P5 = pk2(sacc[T][10], sacc[T][11]);
      unsigned P6 = pk2(sacc[T][12], sacc[T][13]);
      unsigned P7 = pk2(sacc[T][14], sacc[T][15]);
      unsigned R0 = (unsigned)__shfl_xor((int)(h ? P0 : P2), 32, 64);
      unsigned R1 = (unsigned)__shfl_xor((int)(h ? P1 : P3), 32, 64);
      unsigned R2 = (unsigned)__shfl_xor((int)(h ? P4 : P6), 32, 64);
      unsigned R3 = (unsigned)__shfl_xor((int)(h ? P5 : P7), 32, 64);
      u32x4 lo, hi;
      lo[0] = h ? R0 : P0; lo[1] = h ? R1 : P1; lo[2] = h ? P2 : R0; lo[3] = h ? P3 : R1;
      hi[0] = h ? R2 : P4; hi[1] = h ? R3 : P5; hi[2] = h ? P6 : R2; hi[3] = h ? P7 : R3;
      pf[2 * T] = __builtin_bit_cast(s16x8, lo);
      pf[2 * T + 1] = __builtin_bit_cast(s16x8, hi);
    }

#pragma unroll
    for (int r = 0; r < 16; r++) {
      oacc[0][r] *= alpha;
      oacc[1][r] *= alpha;
    }

#pragma unroll
    for (int kc = 0; kc < 8; kc++) {
#pragma unroll
      for (int td = 0; td < 2; td++) {
        s16x8 vf = *(const s16x8*)(Vs + (td * 32 + l31) * 128 + (((2 * kc + h) ^ (l31 & 15)) * 8));
        oacc[td] = __builtin_amdgcn_mfma_f32_32x32x16_bf16(vf, pf[kc], oacc[td], 0, 0, 0);
      }
    }
  }

  // ---- epilogue: lane-local 1/l, transpose O^T -> O via padded LDS, coalesced store ----
  __syncthreads();  // all waves done reading K/V buffers
  const int b = bh >> 4, head = bh & 15;
  float inv = rcpfast(l_own);
  const int g = lane >> 3, d4 = (lane & 7) * 4;
#pragma unroll
  for (int td = 0; td < 2; td++) {
    float* tb = (float*)Smem + (size_t)(wave * 2 + td) * 1056;  // 32 d-rows x 33 (pad)
#pragma unroll
    for (int r = 0; r < 16; r++) {
      int d_loc = (r & 3) + 8 * (r >> 2) + 4 * h;
      tb[d_loc * 33 + l31] = oacc[td][r] * inv;
    }
    // same-wave DS ops are in-order: reads below see all lanes' writes above
#pragma unroll
    for (int j = 0; j < 4; j++) {
      int qq = j * 8 + g;
      float x0 = tb[(d4 + 0) * 33 + qq];
      float x1 = tb[(d4 + 1) * 33 + qq];
      float x2 = tb[(d4 + 2) * 33 + qq];
      float x3 = tb[(d4 + 3) * 33 + qq];
      uint2 pkd;
      pkd.x = (unsigned)f2bf(x0) | ((unsigned)f2bf(x1) << 16);
      pkd.y = (unsigned)f2bf(x2) | ((unsigned)f2bf(x3) << 16);
      int q = q0 + wave * 32 + qq;
      *(uint2*)(O + ((size_t)(b * SEQ + q)) * DM + head * DH + td * 32 + d4) = pkd;
    }
  }
}

// ---------------- host launch ----------------
extern "C" void kernel_launch(void* const* d_in, const int* in_sizes, int n_in,
                              void* d_out, int out_size, void* d_ws, size_t ws_size,
                              hipStream_t stream) {
  const float* x  = (const float*)d_in[0];
  const float* wq = (const float*)d_in[1];
  const float* wk = (const float*)d_in[2];
  const float* wv = (const float*)d_in[3];
  const float* wo = (const float*)d_in[4];

  short* ws = (short*)d_ws;
  short* Xb  = ws;
  short* Wqb = Xb + (size_t)NROWS * DM;     // 4 weights contiguous from here
  short* Wkb = Wqb + (size_t)DM * DM;
  short* Wvb = Wkb + (size_t)DM * DM;
  short* Wob = Wvb + (size_t)DM * DM;
  short* Qb  = Wob + (size_t)DM * DM;       // [B,NH,SEQ,DH]
  short* Kb  = Qb + (size_t)NROWS * DM;
  short* Vtb = Kb + (size_t)NROWS * DM;     // [B,NH,DH,SEQ]
  short* Ob  = Xb;                          // alias: X dead after QKV GEMMs

  int total_chunks = NROWS * DM / 8 + 4 * (DM * DM / 8);
  cast_all<<<total_chunks / 256, 256, 0, stream>>>(x, wq, wk, wv, wo, Xb, Wqb);

  gemm_qkv<<<dim3(24, 64), 256, 0, stream>>>(Xb, Wqb, Wkb, Wvb, Qb, Kb, Vtb);

  attn_kernel<<<1024, 256, 0, stream>>>(Qb, Kb, Vtb, Ob);

  gemm_o<<<dim3(8, 64), 256, 0, stream>>>(Ob, Wob, (float*)d_out);
}

// Round 6
// 270.457 us; speedup vs baseline: 1.1701x; 1.1445x over previous
//
#include <hip/hip_runtime.h>
#include <stdint.h>
#include <stddef.h>

#define SEQ 2048
#define NH 16
#define DH 64
#define DM 1024
#define NROWS 8192  // B*T

typedef __attribute__((ext_vector_type(4))) float f32x4;
typedef __attribute__((ext_vector_type(16))) float f32x16;
typedef __attribute__((ext_vector_type(8))) short s16x8;
typedef __attribute__((ext_vector_type(4))) unsigned u32x4;

__device__ __forceinline__ unsigned short f2bf(float f) {
  unsigned int u = __builtin_bit_cast(unsigned int, f);
  u += 0x7fffu + ((u >> 16) & 1u);
  return (unsigned short)(u >> 16);
}

__device__ __forceinline__ float exp2fast(float x) {
#if __has_builtin(__builtin_amdgcn_exp2f)
  return __builtin_amdgcn_exp2f(x);
#else
  return exp2f(x);
#endif
}

__device__ __forceinline__ float rcpfast(float x) {
#if __has_builtin(__builtin_amdgcn_rcpf)
  return __builtin_amdgcn_rcpf(x);
#else
  return 1.0f / x;
#endif
}

// pack two f32 -> (bf16(lo) | bf16(hi)<<16), truncating (P in (0,1], rel err < 2^-8)
__device__ __forceinline__ unsigned pk2(float lo, float hi) {
  return __builtin_amdgcn_perm(__builtin_bit_cast(unsigned, hi),
                               __builtin_bit_cast(unsigned, lo), 0x07060302u);
}

__device__ __forceinline__ void async16(const void* g, void* l) {
  __builtin_amdgcn_global_load_lds(
      (const __attribute__((address_space(1))) unsigned int*)g,
      (__attribute__((address_space(3))) unsigned int*)l, 16, 0, 0);
}

// ---------------- fused fp32 -> bf16 cast: x + 4 weights, one launch ----------------
__global__ __launch_bounds__(256) void cast_all(const float* __restrict__ x,
                                                const float* __restrict__ w0,
                                                const float* __restrict__ w1,
                                                const float* __restrict__ w2,
                                                const float* __restrict__ w3,
                                                short* __restrict__ Xb,
                                                short* __restrict__ Wb) {
  int g = blockIdx.x * 256 + threadIdx.x;  // chunk of 8 floats
  const float* src;
  short* dst;
  int off;
  if (g < NROWS * DM / 8) {
    src = x; dst = Xb; off = g;
  } else {
    int r = g - NROWS * DM / 8;
    int w = r >> 17;             // 0..3  (DM*DM/8 = 131072 chunks per weight)
    off = r & 131071;
    src = (w == 0) ? w0 : (w == 1) ? w1 : (w == 2) ? w2 : w3;
    dst = Wb + ((size_t)w << 20);
  }
  const float4* s4 = (const float4*)src;
  float4 a = s4[2 * off], b = s4[2 * off + 1];
  s16x8 o;
  o[0] = (short)f2bf(a.x); o[1] = (short)f2bf(a.y);
  o[2] = (short)f2bf(a.z); o[3] = (short)f2bf(a.w);
  o[4] = (short)f2bf(b.x); o[5] = (short)f2bf(b.y);
  o[6] = (short)f2bf(b.z); o[7] = (short)f2bf(b.w);
  *(s16x8*)(dst + (size_t)8 * off) = o;
}

// ---------------- FUSED QKV projection GEMM ----------------
// One block computes the Q, K, AND V 128x128 output tiles for its (bm, bn):
// X tile staged ONCE per k-chunk for all three -> staged bytes drop from 6 to 4
// tiles per output-triple (256 -> 170 B/MFMA). Staging path is the measured
// bottleneck (6.5 TB/s chip ceiling, R5). LDS 64KB (X + 3 W), 2 blocks/CU,
// XOR-swizzled rows (R5: zero conflicts). acc = 3x16 f32x4 = 192 VGPR ->
// launch_bounds(256,2); ks-outer/g-inner keeps live fragments minimal.
__global__ __launch_bounds__(256, 2) void gemm_qkv(const short* __restrict__ X,
                                                   const short* __restrict__ Wq,
                                                   const short* __restrict__ Wk,
                                                   const short* __restrict__ Wv,
                                                   short* __restrict__ Qo,
                                                   short* __restrict__ Ko,
                                                   short* __restrict__ Vo) {
  __shared__ __align__(16) short Xs[128 * 64];
  __shared__ __align__(16) short Ws[3][128 * 64];
  const int tid = threadIdx.x;
  const int lane = tid & 63, wave = tid >> 6;
  const int l15 = lane & 15, quad = lane >> 4;
  const int bn = blockIdx.x * 128;
  const int bm = blockIdx.y * 128;
  const int wm = (wave >> 1) * 64, wn = (wave & 1) * 64;

  const short* Ab = X + (size_t)bm * DM;
  const short* W0 = Wq + (size_t)bn * DM;
  const short* W1 = Wk + (size_t)bn * DM;
  const short* W2 = Wv + (size_t)bn * DM;

  f32x4 acc[3][4][4];
#pragma unroll
  for (int g = 0; g < 3; g++)
#pragma unroll
    for (int i = 0; i < 4; i++)
#pragma unroll
      for (int j = 0; j < 4; j++) acc[g][i][j] = (f32x4)0.f;

  for (int k0 = 0; k0 < DM; k0 += 64) {
#pragma unroll
    for (int i = 0; i < 4; i++) {
      int f = i * 256 + tid;
      int row = f >> 3, c = ((f & 7) ^ (row & 7)) * 8;
      async16(Ab + (size_t)row * DM + k0 + c, Xs + (size_t)f * 8);
      async16(W0 + (size_t)row * DM + k0 + c, &Ws[0][(size_t)f * 8]);
      async16(W1 + (size_t)row * DM + k0 + c, &Ws[1][(size_t)f * 8]);
      async16(W2 + (size_t)row * DM + k0 + c, &Ws[2][(size_t)f * 8]);
    }
    __syncthreads();
#pragma unroll
    for (int ks = 0; ks < 2; ks++) {
      s16x8 af[4];
#pragma unroll
      for (int t = 0; t < 4; t++)
        af[t] = *(const s16x8*)(Xs + (wm + t * 16 + l15) * 64 + (((ks * 4 + quad) ^ (l15 & 7)) * 8));
#pragma unroll
      for (int g = 0; g < 3; g++) {
        s16x8 bfr[4];
#pragma unroll
        for (int t = 0; t < 4; t++)
          bfr[t] = *(const s16x8*)(&Ws[g][(wn + t * 16 + l15) * 64 + (((ks * 4 + quad) ^ (l15 & 7)) * 8)]);
#pragma unroll
        for (int mt = 0; mt < 4; mt++)
#pragma unroll
          for (int nt = 0; nt < 4; nt++) {
            if (g == 2)  // V: swap operands so tokens land in lanes (coalesced V^T store)
              acc[2][mt][nt] = __builtin_amdgcn_mfma_f32_16x16x32_bf16(bfr[nt], af[mt], acc[2][mt][nt], 0, 0, 0);
            else
              acc[g][mt][nt] = __builtin_amdgcn_mfma_f32_16x16x32_bf16(af[mt], bfr[nt], acc[g][mt][nt], 0, 0, 0);
          }
      }
    }
    __syncthreads();
  }

  // Q, K: [B,NH,SEQ,DH] scatter
#pragma unroll
  for (int g = 0; g < 2; g++) {
    short* Dst = g ? Ko : Qo;
#pragma unroll
    for (int mt = 0; mt < 4; mt++)
#pragma unroll
      for (int r = 0; r < 4; r++)
#pragma unroll
        for (int nt = 0; nt < 4; nt++) {
          int m = bm + wm + mt * 16 + quad * 4 + r;
          int n = bn + wn + nt * 16 + l15;
          int b = m >> 11, t = m & (SEQ - 1);
          int hh = n >> 6, d = n & 63;
          Dst[((((size_t)b * NH + hh) * SEQ + t) << 6) + d] = (short)f2bf(acc[g][mt][nt][r]);
        }
  }
  // V: [B,NH,DH,SEQ] (transposed D: col = token, row = d)
#pragma unroll
  for (int mt = 0; mt < 4; mt++)
#pragma unroll
    for (int r = 0; r < 4; r++)
#pragma unroll
      for (int nt = 0; nt < 4; nt++) {
        int n = bn + wn + nt * 16 + quad * 4 + r;  // d-dim
        int m = bm + wm + mt * 16 + l15;           // token
        int b = m >> 11, t = m & (SEQ - 1);
        int hh = n >> 6, d = n & 63;
        Vo[(((size_t)b * NH + hh) * DH + d) * SEQ + t] = (short)f2bf(acc[2][mt][nt][r]);
      }
}

// ---------------- output projection GEMM, 256x128 supertile, fp32 out ----------------
// 256-row M-tile: staged (256+128) rows per iter vs 2x(128+128) for two 128-tiles
// -> 187 B/MFMA vs 256. LDS 48KB, grid (8,32).
__global__ __launch_bounds__(256, 2) void gemm_o(const short* __restrict__ A,
                                                 const short* __restrict__ B,
                                                 float* __restrict__ C) {
  __shared__ __align__(16) short As[256 * 64];
  __shared__ __align__(16) short Bs[128 * 64];
  const int tid = threadIdx.x;
  const int lane = tid & 63, wave = tid >> 6;
  const int l15 = lane & 15, quad = lane >> 4;
  const int bm = blockIdx.y * 256, bn = blockIdx.x * 128;
  const int wm = (wave >> 1) * 128, wn = (wave & 1) * 64;

  const short* Ab = A + (size_t)bm * DM;
  const short* Bb = B + (size_t)bn * DM;

  f32x4 acc[8][4];
#pragma unroll
  for (int i = 0; i < 8; i++)
#pragma unroll
    for (int j = 0; j < 4; j++) acc[i][j] = (f32x4)0.f;

  for (int k0 = 0; k0 < DM; k0 += 64) {
#pragma unroll
    for (int i = 0; i < 8; i++) {
      int f = i * 256 + tid;
      int row = f >> 3, c = ((f & 7) ^ (row & 7)) * 8;
      async16(Ab + (size_t)row * DM + k0 + c, As + (size_t)f * 8);
    }
#pragma unroll
    for (int i = 0; i < 4; i++) {
      int f = i * 256 + tid;
      int row = f >> 3, c = ((f & 7) ^ (row & 7)) * 8;
      async16(Bb + (size_t)row * DM + k0 + c, Bs + (size_t)f * 8);
    }
    __syncthreads();
#pragma unroll
    for (int ks = 0; ks < 2; ks++) {
      s16x8 bfr[4];
#pragma unroll
      for (int t = 0; t < 4; t++)
        bfr[t] = *(const s16x8*)(Bs + (wn + t * 16 + l15) * 64 + (((ks * 4 + quad) ^ (l15 & 7)) * 8));
#pragma unroll
      for (int mt = 0; mt < 8; mt++) {
        s16x8 af = *(const s16x8*)(As + (wm + mt * 16 + l15) * 64 + (((ks * 4 + quad) ^ (l15 & 7)) * 8));
#pragma unroll
        for (int nt = 0; nt < 4; nt++)
          acc[mt][nt] = __builtin_amdgcn_mfma_f32_16x16x32_bf16(af, bfr[nt], acc[mt][nt], 0, 0, 0);
      }
    }
    __syncthreads();
  }

#pragma unroll
  for (int mt = 0; mt < 8; mt++)
#pragma unroll
    for (int r = 0; r < 4; r++) {
      int m = bm + wm + mt * 16 + quad * 4 + r;
#pragma unroll
      for (int nt = 0; nt < 4; nt++)
        C[(size_t)m * DM + bn + wn + nt * 16 + l15] = acc[mt][nt][r];
    }
}

// ---------------- causal flash attention (R3 version: 92.6us measured) ----------------
__global__ __launch_bounds__(256, 2) void attn_kernel(const short* __restrict__ Q,
                                                      const short* __restrict__ K,
                                                      const short* __restrict__ V,
                                                      short* __restrict__ O) {
  __shared__ __align__(16) short Smem[2 * 16384];  // 2 x (K 16KB + V 16KB) = 64KB

  const int tid = threadIdx.x;
  const int lane = tid & 63, wave = tid >> 6;
  const int l31 = lane & 31, h = lane >> 5;

  const int c = blockIdx.x & 7, s = blockIdx.x >> 3;
  const int bh = c * 8 + (s >> 4);
  const int qt = 15 - (s & 15);
  const int q0 = qt * 128;

  const short* Qb = Q + (size_t)bh * SEQ * DH;
  const short* Kb = K + (size_t)bh * SEQ * DH;
  const short* Vb = V + (size_t)bh * DH * SEQ;

  auto stage = [&](int ktile, int bufsel) {
    short* base = Smem + bufsel * 16384;
    const short* ksrc = Kb + (size_t)ktile * 128 * DH;
#pragma unroll
    for (int i = 0; i < 4; i++) {
      int f = i * 256 + tid;
      int kk = f >> 3, c8 = (f & 7) ^ (kk & 7);
      async16(ksrc + (size_t)kk * DH + c8 * 8, base + (size_t)f * 8);
    }
    const short* vsrc = Vb + (size_t)ktile * 128;
#pragma unroll
    for (int i = 0; i < 4; i++) {
      int f = i * 256 + tid;
      int d = f >> 4, c16 = (f & 15) ^ (d & 15);
      async16(vsrc + (size_t)d * SEQ + c16 * 8, base + 8192 + (size_t)f * 8);
    }
  };

  s16x8 qf[4];
#pragma unroll
  for (int ks = 0; ks < 4; ks++)
    qf[ks] = *(const s16x8*)(Qb + (size_t)(q0 + wave * 32 + l31) * DH + ks * 16 + h * 8);

  f32x16 oacc[2];
  oacc[0] = (f32x16)0.f;
  oacc[1] = (f32x16)0.f;
  float m_own = -3.0e38f, l_own = 0.f;
  const float C = 0.18033688011112042f;  // (1/sqrt(64)) * log2(e)

  stage(0, 0);

  for (int kt = 0; kt <= qt; kt++) {
    const int cur = kt & 1;
    __syncthreads();
    if (kt < qt) stage(kt + 1, cur ^ 1);
    const short* Ks = Smem + cur * 16384;
    const short* Vs = Ks + 8192;

    f32x16 sacc[4];
#pragma unroll
    for (int T = 0; T < 4; T++) sacc[T] = (f32x16)0.f;
#pragma unroll
    for (int ks = 0; ks < 4; ks++) {
#pragma unroll
      for (int T = 0; T < 4; T++) {
        s16x8 kf = *(const s16x8*)(Ks + (T * 32 + l31) * 64 + (((2 * ks + h) ^ (l31 & 7)) * 8));
        sacc[T] = __builtin_amdgcn_mfma_f32_32x32x16_bf16(kf, qf[ks], sacc[T], 0, 0, 0);
      }
    }

    if (kt == qt) {
      int limit = wave * 32 + l31 - 4 * h;
#pragma unroll
      for (int T = 0; T < 4; T++)
#pragma unroll
        for (int r = 0; r < 16; r++) {
          int kkc = T * 32 + (r & 3) + 8 * (r >> 2);
          if (kkc > limit) sacc[T][r] = -3.0e38f;
        }
    }

    float tm[4];
#pragma unroll
    for (int T = 0; T < 4; T++) {
      float a = fmaxf(fmaxf(sacc[T][0], sacc[T][1]), fmaxf(sacc[T][2], sacc[T][3]));
      float b = fmaxf(fmaxf(sacc[T][4], sacc[T][5]), fmaxf(sacc[T][6], sacc[T][7]));
      float cc = fmaxf(fmaxf(sacc[T][8], sacc[T][9]), fmaxf(sacc[T][10], sacc[T][11]));
      float d = fmaxf(fmaxf(sacc[T][12], sacc[T][13]), fmaxf(sacc[T][14], sacc[T][15]));
      tm[T] = fmaxf(fmaxf(a, b), fmaxf(cc, d));
    }
    float mx = fmaxf(fmaxf(tm[0], tm[1]), fmaxf(tm[2], tm[3]));
    mx = fmaxf(mx, __shfl_xor(mx, 32, 64));
    float mnew = fmaxf(m_own, mx);
    float mb = mnew * C;
    float alpha = exp2fast(m_own * C - mb);
    m_own = mnew;

    float ts[4];
#pragma unroll
    for (int T = 0; T < 4; T++) {
#pragma unroll
      for (int r = 0; r < 16; r++) sacc[T][r] = exp2fast(fmaf(sacc[T][r], C, -mb));
      float a = (sacc[T][0] + sacc[T][1]) + (sacc[T][2] + sacc[T][3]);
      float b = (sacc[T][4] + sacc[T][5]) + (sacc[T][6] + sacc[T][7]);
      float cc = (sacc[T][8] + sacc[T][9]) + (sacc[T][10] + sacc[T][11]);
      float d = (sacc[T][12] + sacc[T][13]) + (sacc[T][14] + sacc[T][15]);
      ts[T] = (a + b) + (cc + d);
    }
    float rsum = (ts[0] + ts[1]) + (ts[2] + ts[3]);
    rsum += __shfl_xor(rsum, 32, 64);
    l_own = l_own * alpha + rsum;

    s16x8 pf[8];
#pragma unroll
    for (int T = 0; T < 4; T++) {
      unsigned P0 = pk2(sacc[T][0], sacc[T][1]);
      unsigned P1 = pk2(sacc[T][2], sacc[T][3]);
      unsigned P2 = pk2(sacc[T][4], sacc[T][5]);
      unsigned P3 = pk2(sacc[T][6], sacc[T][7]);
      unsigned P4 = pk2(sacc[T][8], sacc[T][9]);
      unsigned P5 = pk2(sacc[T][10], sacc[T][11]);
      unsigned P6 = pk2(sacc[T][12], sacc[T][13]);
      unsigned P7 = pk2(sacc[T][14], sacc[T][15]);
      unsigned R0 = (unsigned)__shfl_xor((int)(h ? P0 : P2), 32, 64);
      unsigned R1 = (unsigned)__shfl_xor((int)(h ? P1 : P3), 32, 64);
      unsigned R2 = (unsigned)__shfl_xor((int)(h ? P4 : P6), 32, 64);
      unsigned R3 = (unsigned)__shfl_xor((int)(h ? P5 : P7), 32, 64);
      u32x4 lo, hi;
      lo[0] = h ? R0 : P0; lo[1] = h ? R1 : P1; lo[2] = h ? P2 : R0; lo[3] = h ? P3 : R1;
      hi[0] = h ? R2 : P4; hi[1] = h ? R3 : P5; hi[2] = h ? P6 : R2; hi[3] = h ? P7 : R3;
      pf[2 * T] = __builtin_bit_cast(s16x8, lo);
      pf[2 * T + 1] = __builtin_bit_cast(s16x8, hi);
    }

#pragma unroll
    for (int r = 0; r < 16; r++) {
      oacc[0][r] *= alpha;
      oacc[1][r] *= alpha;
    }

#pragma unroll
    for (int kc = 0; kc < 8; kc++) {
#pragma unroll
      for (int td = 0; td < 2; td++) {
        s16x8 vf = *(const s16x8*)(Vs + (td * 32 + l31) * 128 + (((2 * kc + h) ^ (l31 & 15)) * 8));
        oacc[td] = __builtin_amdgcn_mfma_f32_32x32x16_bf16(vf, pf[kc], oacc[td], 0, 0, 0);
      }
    }
  }

  __syncthreads();
  const int b = bh >> 4, head = bh & 15;
  float inv = rcpfast(l_own);
  const int g = lane >> 3, d4 = (lane & 7) * 4;
#pragma unroll
  for (int td = 0; td < 2; td++) {
    float* tb = (float*)Smem + (size_t)(wave * 2 + td) * 1056;  // 32 d-rows x 33 (pad)
#pragma unroll
    for (int r = 0; r < 16; r++) {
      int d_loc = (r & 3) + 8 * (r >> 2) + 4 * h;
      tb[d_loc * 33 + l31] = oacc[td][r] * inv;
    }
#pragma unroll
    for (int j = 0; j < 4; j++) {
      int qq = j * 8 + g;
      float x0 = tb[(d4 + 0) * 33 + qq];
      float x1 = tb[(d4 + 1) * 33 + qq];
      float x2 = tb[(d4 + 2) * 33 + qq];
      float x3 = tb[(d4 + 3) * 33 + qq];
      uint2 pkd;
      pkd.x = (unsigned)f2bf(x0) | ((unsigned)f2bf(x1) << 16);
      pkd.y = (unsigned)f2bf(x2) | ((unsigned)f2bf(x3) << 16);
      int q = q0 + wave * 32 + qq;
      *(uint2*)(O + ((size_t)(b * SEQ + q)) * DM + head * DH + td * 32 + d4) = pkd;
    }
  }
}

// ---------------- host launch ----------------
extern "C" void kernel_launch(void* const* d_in, const int* in_sizes, int n_in,
                              void* d_out, int out_size, void* d_ws, size_t ws_size,
                              hipStream_t stream) {
  const float* x  = (const float*)d_in[0];
  const float* wq = (const float*)d_in[1];
  const float* wk = (const float*)d_in[2];
  const float* wv = (const float*)d_in[3];
  const float* wo = (const float*)d_in[4];

  short* ws = (short*)d_ws;
  short* Xb  = ws;
  short* Wqb = Xb + (size_t)NROWS * DM;     // 4 weights contiguous from here
  short* Wkb = Wqb + (size_t)DM * DM;
  short* Wvb = Wkb + (size_t)DM * DM;
  short* Wob = Wvb + (size_t)DM * DM;
  short* Qb  = Wob + (size_t)DM * DM;       // [B,NH,SEQ,DH]
  short* Kb  = Qb + (size_t)NROWS * DM;
  short* Vtb = Kb + (size_t)NROWS * DM;     // [B,NH,DH,SEQ]
  short* Ob  = Xb;                          // alias: X dead after QKV GEMMs

  int total_chunks = NROWS * DM / 8 + 4 * (DM * DM / 8);
  cast_all<<<total_chunks / 256, 256, 0, stream>>>(x, wq, wk, wv, wo, Xb, Wqb);

  gemm_qkv<<<dim3(8, 64), 256, 0, stream>>>(Xb, Wqb, Wkb, Wvb, Qb, Kb, Vtb);

  attn_kernel<<<1024, 256, 0, stream>>>(Qb, Kb, Vtb, Ob);

  gemm_o<<<dim3(8, 32), 256, 0, stream>>>(Ob, Wob, (float*)d_out);
}